// Round 2
// baseline (76.091 us; speedup 1.0000x reference)
//
#include <hip/hip_runtime.h>
#include <hip/hip_bf16.h>
#include <math.h>

#define B_ 128
#define C_ 8
#define T_ 128
#define K_ 20
#define S_ 128

#define CC_ROW 396          // padded x row stride (floats) for cc path
#define DTW_TILE_F 1152     // floats per dtw wave tile: xlo 512 | xhi 512 | X2 128
#define SMEM_BYTES 18816    // max(4*4608, cc usage) rounded up

// Fused kernel: 256 threads.
//  - blocks with u%5==0  : DTW for 4 pairs (one per wave), wavefront-pipelined.
//  - other blocks        : cross-correlation for one pair.
__global__ __launch_bounds__(256) void fused_kernel(const float* __restrict__ x,
                                                    const float* __restrict__ bary,
                                                    const float* __restrict__ top_dist,
                                                    const float* __restrict__ bottom_cc,
                                                    int* __restrict__ dtw_gt,
                                                    int* __restrict__ cc_fail) {
    __shared__ __align__(16) unsigned char smem[SMEM_BYTES];
    int u = blockIdx.x;
    int tid = threadIdx.x;

    if (u % 5 == 0) {
        // ------------------------- DTW path -------------------------
        int wave = tid >> 6;
        int lane = tid & 63;
        int pair = (u / 5) * 4 + wave;            // 0..2559
        int b = pair / K_;
        int kk = pair - b * K_;
        float* tile = (float*)smem + wave * DTW_TILE_F;

        // Stage x[b] -> plane-split LDS: xlo[t][0..3] at [0,512), xhi at [512,1024).
        #pragma unroll
        for (int i = 0; i < 16; ++i) {
            int idx = i * 64 + lane;
            int c = idx >> 7;          // 0..7
            int t = idx & 127;
            float v = x[(b * C_ + c) * T_ + t];
            tile[t * 4 + (c & 3) + ((c >> 2) * 512)] = v;
        }
        __syncthreads();
        // X2[t] = sum_c x[t][c]^2 at [1024,1152)
        #pragma unroll
        for (int rep = 0; rep < 2; ++rep) {
            int t = rep * 64 + lane;
            float4 xa = *(const float4*)&tile[t * 4];
            float4 xb = *(const float4*)&tile[512 + t * 4];
            float s = xa.x * xa.x;
            s = fmaf(xa.y, xa.y, s); s = fmaf(xa.z, xa.z, s); s = fmaf(xa.w, xa.w, s);
            s = fmaf(xb.x, xb.x, s); s = fmaf(xb.y, xb.y, s); s = fmaf(xb.z, xb.z, s);
            s = fmaf(xb.w, xb.w, s);
            tile[1024 + t] = s;
        }
        __syncthreads();

        // Barycenter columns s0=2*lane, s1=2*lane+1: B2 and -2*b in registers.
        float bv0[8], bv1[8], B20, B21;
        {
            const float4* bp = (const float4*)(bary + (size_t)(kk * S_ + 2 * lane) * C_);
            float4 q0 = bp[0], q1 = bp[1], q2 = bp[2], q3 = bp[3];
            bv0[0]=q0.x; bv0[1]=q0.y; bv0[2]=q0.z; bv0[3]=q0.w;
            bv0[4]=q1.x; bv0[5]=q1.y; bv0[6]=q1.z; bv0[7]=q1.w;
            bv1[0]=q2.x; bv1[1]=q2.y; bv1[2]=q2.z; bv1[3]=q2.w;
            bv1[4]=q3.x; bv1[5]=q3.y; bv1[6]=q3.z; bv1[7]=q3.w;
            float s0 = 0.f, s1 = 0.f;
            #pragma unroll
            for (int ch = 0; ch < 8; ++ch) {
                s0 = fmaf(bv0[ch], bv0[ch], s0);
                s1 = fmaf(bv1[ch], bv1[ch], s1);
            }
            B20 = s0; B21 = s1;
            #pragma unroll
            for (int ch = 0; ch < 8; ++ch) { bv0[ch] *= -2.f; bv1[ch] *= -2.f; }
        }

        const float INF = __builtin_inff();
        float c0 = INF, c1 = INF, lcp = INF;   // lcp = lc from previous step (diag)
        bool is0 = (lane == 0);

        // d = 0: only lane 0 (t=0, virtual diag D[-1][-1]=0).
        if (is0) {
            float bse = tile[1024];
            float4 xa = *(const float4*)&tile[0];
            float4 xb = *(const float4*)&tile[512];
            float a0 = bse + B20, a1 = bse + B21;
            a0 = fmaf(bv0[0], xa.x, a0); a0 = fmaf(bv0[1], xa.y, a0);
            a0 = fmaf(bv0[2], xa.z, a0); a0 = fmaf(bv0[3], xa.w, a0);
            a0 = fmaf(bv0[4], xb.x, a0); a0 = fmaf(bv0[5], xb.y, a0);
            a0 = fmaf(bv0[6], xb.z, a0); a0 = fmaf(bv0[7], xb.w, a0);
            a1 = fmaf(bv1[0], xa.x, a1); a1 = fmaf(bv1[1], xa.y, a1);
            a1 = fmaf(bv1[2], xa.z, a1); a1 = fmaf(bv1[3], xa.w, a1);
            a1 = fmaf(bv1[4], xb.x, a1); a1 = fmaf(bv1[5], xb.y, a1);
            a1 = fmaf(bv1[6], xb.z, a1); a1 = fmaf(bv1[7], xb.w, a1);
            c0 = fmaxf(a0, 0.f);
            c1 = fmaxf(a1, 0.f) + c0;
        }

        for (int d = 1; d < T_ + 63; ++d) {
            float lcs = __shfl_up(c1, 1);
            float lc = is0 ? INF : lcs;        // left edge for lane 0
            int t = d - lane;
            if (t >= 0) {
                int tc = (t < 127) ? t : 127;  // clamp; garbage stays in garbage region
                float bse = tile[1024 + tc];
                float4 xa = *(const float4*)&tile[tc * 4];
                float4 xb = *(const float4*)&tile[512 + tc * 4];
                float a0 = bse + B20, a1 = bse + B21;
                a0 = fmaf(bv0[0], xa.x, a0); a0 = fmaf(bv0[1], xa.y, a0);
                a0 = fmaf(bv0[2], xa.z, a0); a0 = fmaf(bv0[3], xa.w, a0);
                a0 = fmaf(bv0[4], xb.x, a0); a0 = fmaf(bv0[5], xb.y, a0);
                a0 = fmaf(bv0[6], xb.z, a0); a0 = fmaf(bv0[7], xb.w, a0);
                a1 = fmaf(bv1[0], xa.x, a1); a1 = fmaf(bv1[1], xa.y, a1);
                a1 = fmaf(bv1[2], xa.z, a1); a1 = fmaf(bv1[3], xa.w, a1);
                a1 = fmaf(bv1[4], xb.x, a1); a1 = fmaf(bv1[5], xb.y, a1);
                a1 = fmaf(bv1[6], xb.z, a1); a1 = fmaf(bv1[7], xb.w, a1);
                a0 = fmaxf(a0, 0.f);
                a1 = fmaxf(a1, 0.f);
                // up = c0/c1 (old), diag = lcp / old c0, left = lc / new c0
                float n0 = a0 + fminf(fminf(c0, lcp), lc);
                float n1 = a1 + fminf(fminf(c1, c0), n0);
                c0 = n0; c1 = n1;
            }
            lcp = lc;
        }

        if (lane == 63)
            dtw_gt[pair] = (logf(c1) > top_dist[kk]) ? 1 : 0;
    } else {
        // ------------------------- CC path -------------------------
        int pair = u - (u + 4) / 5;               // 0..2559
        int b = pair / K_;
        int kk = pair - b * K_;

        float* xp = (float*)smem;                 // [C_ * CC_ROW] zero-padded
        float* bt = xp + C_ * CC_ROW;             // [C_][S_]
        int* fail = (int*)(bt + C_ * S_);

        if (tid == 0) *fail = 0;

        for (int i = tid; i < C_ * CC_ROW; i += 256) {
            int c = i / CC_ROW;
            int j = i - c * CC_ROW;
            int t = j - (S_ - 1);
            float v = 0.0f;
            if (t >= 0 && t < T_) v = x[(b * C_ + c) * T_ + t];
            xp[i] = v;
        }
        for (int i = tid; i < C_ * S_; i += 256) {
            int s = i >> 3;
            int c = i & 7;
            bt[c * S_ + s] = bary[(kk * S_ + s) * C_ + c];
        }
        __syncthreads();

        int c = tid >> 5;
        int l = tid & 31;
        int lag0 = l * 8;
        const float* xr = &xp[c * CC_ROW];
        const float* br = &bt[c * S_];

        float w[12];
        #pragma unroll
        for (int i = 0; i < 12; i += 4) {
            float4 v4 = *(const float4*)(xr + lag0 + i);
            w[i] = v4.x; w[i+1] = v4.y; w[i+2] = v4.z; w[i+3] = v4.w;
        }
        float acc[8] = {0.f,0.f,0.f,0.f,0.f,0.f,0.f,0.f};

        #pragma unroll
        for (int s4 = 0; s4 < S_; s4 += 4) {
            #pragma unroll
            for (int uu = 0; uu < 4; ++uu) {
                float bval = br[s4 + uu];
                #pragma unroll
                for (int j = 0; j < 8; ++j)
                    acc[j] = fmaf(w[uu + j], bval, acc[j]);
            }
            #pragma unroll
            for (int i = 0; i < 8; ++i) w[i] = w[i + 4];
            float4 v4 = *(const float4*)(xr + lag0 + s4 + 12);
            w[8] = v4.x; w[9] = v4.y; w[10] = v4.z; w[11] = v4.w;
        }

        if (l == 31) acc[7] = -__builtin_inff();   // lag 255 doesn't exist
        float m = acc[0];
        #pragma unroll
        for (int j = 1; j < 8; ++j) m = fmaxf(m, acc[j]);
        #pragma unroll
        for (int off = 16; off > 0; off >>= 1)
            m = fmaxf(m, __shfl_xor(m, off));

        if (l == 0) {
            if (m <= bottom_cc[kk * C_ + c]) atomicOr(fail, 1);
        }
        __syncthreads();
        if (tid == 0) cc_fail[pair] = *fail;
    }
}

__global__ void final_kernel(const int* __restrict__ preds,
                             const int* __restrict__ dtw_gt,
                             const int* __restrict__ cc_fail,
                             int* __restrict__ out) {
    int b = threadIdx.x;
    if (b < B_) {
        int dtw_all = 1, cc_all = 1;
        #pragma unroll
        for (int k = 0; k < K_; ++k) {
            dtw_all &= dtw_gt[b * K_ + k];
            cc_all &= cc_fail[b * K_ + k];
        }
        out[b] = (dtw_all | cc_all) ? K_ : preds[b];
    }
}

extern "C" void kernel_launch(void* const* d_in, const int* in_sizes, int n_in,
                              void* d_out, int out_size, void* d_ws, size_t ws_size,
                              hipStream_t stream) {
    const float* x         = (const float*)d_in[0];  // [B, C, T]
    const int*   preds     = (const int*)d_in[1];    // [B]
    const float* bary      = (const float*)d_in[2];  // [K, S, C]
    const float* top_dist  = (const float*)d_in[3];  // [K]
    const float* bottom_cc = (const float*)d_in[4];  // [K, C]
    int* out = (int*)d_out;                          // [B] int32

    int* dtw_gt  = (int*)d_ws;           // [B*K]
    int* cc_fail = dtw_gt + B_ * K_;     // [B*K]

    fused_kernel<<<3200, 256, 0, stream>>>(x, bary, top_dist, bottom_cc, dtw_gt, cc_fail);
    final_kernel<<<1, 128, 0, stream>>>(preds, dtw_gt, cc_fail, out);
}

// Round 3
// 65.112 us; speedup vs baseline: 1.1686x; 1.1686x over previous
//
#include <hip/hip_runtime.h>
#include <hip/hip_bf16.h>
#include <math.h>

#define B_ 128
#define C_ 8
#define T_ 128
#define K_ 20
#define S_ 128

#define XROW 384                 // padded cc x row (floats), multiple of 32
#define BTROW 132                // bt row stride: 132%4==0 (float4 ok), 132%32=4 (banks split)
#define SWZ(j) ((j) ^ ((((j) >> 5) & 7) << 2))
#define SMEMF 2080               // floats: dtw needs 1152; cc needs 4*384+4*132=2064

// Uniform 64-thread blocks. u%5==0 -> DTW (wave = 2 pairs, same b, 32 lanes each,
// 4 columns/lane). Else -> CC half-pair (4 channels x 16 lanes, 16 lags/lane).
__global__ __launch_bounds__(64) void fused_kernel(const float* __restrict__ x,
                                                   const float* __restrict__ bary,
                                                   const float* __restrict__ top_dist,
                                                   const float* __restrict__ bottom_cc,
                                                   int* __restrict__ dtw_gt,
                                                   int* __restrict__ cc_fail2) {
    __shared__ __align__(16) float smem[SMEMF];
    const float INF = __builtin_inff();
    int u = blockIdx.x;
    int lane = threadIdx.x;

    if (u % 5 == 0) {
        // ------------------------------ DTW ------------------------------
        int w = u / 5;               // 0..1279
        int b = w / 10;
        int j2 = w - b * 10;         // k-pair index
        int gl = lane & 31;
        int kk = j2 * 2 + (lane >> 5);

        // Stage x[b] -> plane-split tile: xlo[t*4+c] @0, xhi @512, X2 @1024.
        #pragma unroll
        for (int i = 0; i < 4; ++i) {
            int vid = i * 64 + lane;
            int c = vid >> 5;
            int t0 = (vid & 31) << 2;
            float4 v = *(const float4*)(x + ((size_t)b * C_ + c) * T_ + t0);
            float* dst = &smem[(c >> 2) * 512 + (c & 3)];
            dst[(t0 + 0) * 4] = v.x;
            dst[(t0 + 1) * 4] = v.y;
            dst[(t0 + 2) * 4] = v.z;
            dst[(t0 + 3) * 4] = v.w;
        }
        __syncthreads();
        #pragma unroll
        for (int r = 0; r < 2; ++r) {
            int t = r * 64 + lane;
            float4 xa = *(const float4*)&smem[t * 4];
            float4 xb = *(const float4*)&smem[512 + t * 4];
            float s = xa.x * xa.x;
            s = fmaf(xa.y, xa.y, s); s = fmaf(xa.z, xa.z, s); s = fmaf(xa.w, xa.w, s);
            s = fmaf(xb.x, xb.x, s); s = fmaf(xb.y, xb.y, s); s = fmaf(xb.z, xb.z, s);
            s = fmaf(xb.w, xb.w, s);
            smem[1024 + t] = s;
        }
        __syncthreads();

        // Barycenter: 4 columns s=4gl..4gl+3; keep -2*b and B2 in registers.
        float bv[4][8], B2s[4];
        {
            const float4* bp = (const float4*)(bary + ((size_t)kk * S_ + 4 * gl) * C_);
            #pragma unroll
            for (int r = 0; r < 4; ++r) {
                float4 q0 = bp[2 * r], q1 = bp[2 * r + 1];
                bv[r][0] = q0.x; bv[r][1] = q0.y; bv[r][2] = q0.z; bv[r][3] = q0.w;
                bv[r][4] = q1.x; bv[r][5] = q1.y; bv[r][6] = q1.z; bv[r][7] = q1.w;
                float s = 0.f;
                #pragma unroll
                for (int ch = 0; ch < 8; ++ch) s = fmaf(bv[r][ch], bv[r][ch], s);
                B2s[r] = s;
                #pragma unroll
                for (int ch = 0; ch < 8; ++ch) bv[r][ch] *= -2.f;
            }
        }

        bool is0 = (gl == 0);
        float cr0 = INF, cr1 = INF, cr2 = INF, cr3 = INF;
        // Diag for col 0 at t==0: virtual D[-1][-1]=0 (only lane gl==0); INF after.
        float lcp = is0 ? 0.f : INF;

        for (int d = 0; d < T_ + 31; ++d) {
            float lcs = __shfl_up(cr3, 1);   // lane 32 gets lane 31 (wrong k) -> masked by is0
            float lc = is0 ? INF : lcs;
            int t = d - gl;
            if (t >= 0) {
                int tc = (t < T_ - 1) ? t : (T_ - 1);  // clamp; garbage stays local
                float bse = smem[1024 + tc];
                float4 xa = *(const float4*)&smem[tc * 4];
                float4 xb = *(const float4*)&smem[512 + tc * 4];
                float xv[8];
                xv[0] = xa.x; xv[1] = xa.y; xv[2] = xa.z; xv[3] = xa.w;
                xv[4] = xb.x; xv[5] = xb.y; xv[6] = xb.z; xv[7] = xb.w;
                float a0 = bse + B2s[0], a1 = bse + B2s[1];
                float a2 = bse + B2s[2], a3 = bse + B2s[3];
                #pragma unroll
                for (int ch = 0; ch < 8; ++ch) {
                    a0 = fmaf(bv[0][ch], xv[ch], a0);
                    a1 = fmaf(bv[1][ch], xv[ch], a1);
                    a2 = fmaf(bv[2][ch], xv[ch], a2);
                    a3 = fmaf(bv[3][ch], xv[ch], a3);
                }
                a0 = fmaxf(a0, 0.f); a1 = fmaxf(a1, 0.f);
                a2 = fmaxf(a2, 0.f); a3 = fmaxf(a3, 0.f);
                float n0 = a0 + fminf(fminf(cr0, lcp), lc);
                float n1 = a1 + fminf(fminf(cr1, cr0), n0);
                float n2 = a2 + fminf(fminf(cr2, cr1), n1);
                float n3 = a3 + fminf(fminf(cr3, cr2), n2);
                cr0 = n0; cr1 = n1; cr2 = n2; cr3 = n3;
            }
            lcp = lc;
        }

        if (gl == 31)
            dtw_gt[b * K_ + kk] = (logf(cr3) > top_dist[kk]) ? 1 : 0;
    } else {
        // ------------------------------ CC -------------------------------
        int idx = u - u / 5 - 1;       // 0..5119
        int pair = idx >> 1;
        int h = idx & 1;
        int b = pair / K_;
        int kk = pair - b * K_;
        int cbase = h * 4;

        float* xp = smem;              // 4 rows x XROW, XOR-swizzled
        float* bt = smem + 4 * XROW;   // 4 rows x BTROW

        #pragma unroll
        for (int c = 0; c < 4; ++c)
            for (int j = lane; j < XROW; j += 64) {
                int t = j - (S_ - 1);
                float v = 0.f;
                if (t >= 0 && t < T_) v = x[((size_t)b * C_ + cbase + c) * T_ + t];
                xp[c * XROW + SWZ(j)] = v;
            }
        for (int i = lane; i < 4 * S_; i += 64) {
            int s = i >> 2, c = i & 3;
            bt[c * BTROW + s] = bary[((size_t)kk * S_ + s) * C_ + cbase + c];
        }
        __syncthreads();

        int cl = lane >> 4;            // channel within half
        int gl = lane & 15;
        int lag0 = gl << 4;            // 16 lags per lane
        const float* xr = xp + cl * XROW;
        const float* br = bt + cl * BTROW;

        float wdw[20];
        #pragma unroll
        for (int i = 0; i < 5; ++i) {
            float4 v = *(const float4*)&xr[SWZ(lag0 + i * 4)];
            wdw[i * 4 + 0] = v.x; wdw[i * 4 + 1] = v.y;
            wdw[i * 4 + 2] = v.z; wdw[i * 4 + 3] = v.w;
        }
        float acc[16];
        #pragma unroll
        for (int j = 0; j < 16; ++j) acc[j] = 0.f;

        #pragma unroll
        for (int s4 = 0; s4 < S_; s4 += 4) {
            float4 bq = *(const float4*)&br[s4];   // broadcast per 16-lane group
            float bvals[4] = {bq.x, bq.y, bq.z, bq.w};
            #pragma unroll
            for (int uu = 0; uu < 4; ++uu) {
                #pragma unroll
                for (int j = 0; j < 16; ++j)
                    acc[j] = fmaf(wdw[uu + j], bvals[uu], acc[j]);
            }
            if (s4 < S_ - 4) {
                #pragma unroll
                for (int i = 0; i < 16; ++i) wdw[i] = wdw[i + 4];
                float4 v = *(const float4*)&xr[SWZ(lag0 + s4 + 20)];
                wdw[16] = v.x; wdw[17] = v.y; wdw[18] = v.z; wdw[19] = v.w;
            }
        }

        if (gl == 15) acc[15] = -INF;  // lag 255 doesn't exist
        float m = acc[0];
        #pragma unroll
        for (int j = 1; j < 16; ++j) m = fmaxf(m, acc[j]);
        #pragma unroll
        for (int off = 8; off >= 1; off >>= 1)
            m = fmaxf(m, __shfl_xor(m, off));

        bool fail = false;
        if (gl == 0) fail = (m <= bottom_cc[kk * C_ + cbase + cl]);
        unsigned long long bal = __ballot(fail);
        if (lane == 0) cc_fail2[pair * 2 + h] = (bal != 0ULL) ? 1 : 0;
    }
}

__global__ void final_kernel(const int* __restrict__ preds,
                             const int* __restrict__ dtw_gt,
                             const int* __restrict__ cc_fail2,
                             int* __restrict__ out) {
    int b = threadIdx.x;
    if (b < B_) {
        int dtw_all = 1, cc_all = 1;
        #pragma unroll
        for (int k = 0; k < K_; ++k) {
            dtw_all &= dtw_gt[b * K_ + k];
            cc_all &= (cc_fail2[(b * K_ + k) * 2] | cc_fail2[(b * K_ + k) * 2 + 1]);
        }
        out[b] = (dtw_all | cc_all) ? K_ : preds[b];
    }
}

extern "C" void kernel_launch(void* const* d_in, const int* in_sizes, int n_in,
                              void* d_out, int out_size, void* d_ws, size_t ws_size,
                              hipStream_t stream) {
    const float* x         = (const float*)d_in[0];  // [B, C, T]
    const int*   preds     = (const int*)d_in[1];    // [B]
    const float* bary      = (const float*)d_in[2];  // [K, S, C]
    const float* top_dist  = (const float*)d_in[3];  // [K]
    const float* bottom_cc = (const float*)d_in[4];  // [K, C]
    int* out = (int*)d_out;                          // [B] int32

    int* dtw_gt   = (int*)d_ws;                // [B*K]
    int* cc_fail2 = dtw_gt + B_ * K_;          // [B*K*2]

    fused_kernel<<<6400, 64, 0, stream>>>(x, bary, top_dist, bottom_cc, dtw_gt, cc_fail2);
    final_kernel<<<1, 128, 0, stream>>>(preds, dtw_gt, cc_fail2, out);
}